// Round 9
// baseline (390.526 us; speedup 1.0000x reference)
//
#include <hip/hip_runtime.h>
#include <math.h>

#define NN 20000
#define NE 160000
#define SLOT 40

typedef _Float16 f16;
typedef __attribute__((ext_vector_type(8))) _Float16 f16x8;
typedef __attribute__((ext_vector_type(4))) float f32x4;

__device__ __forceinline__ float leakyf(float x, float s){ return x >= 0.f ? x : s*x; }
__device__ __forceinline__ ushort f2h(float x){ f16 h = (f16)x; ushort u; __builtin_memcpy(&u,&h,2); return u; }
__device__ __forceinline__ float h2f(ushort u){ f16 h; __builtin_memcpy(&h,&u,2); return (float)h; }

__device__ __forceinline__ void gload_lds16(const void* g, void* l){
  __builtin_amdgcn_global_load_lds((const __attribute__((address_space(1))) uint*)g,
                                   (__attribute__((address_space(3))) uint*)l, 16, 0, 0);
}
__device__ __forceinline__ void nts4(float* p, f32x4 v){
  __builtin_nontemporal_store(v, (f32x4*)p);
}

// prep blocks: [0,168) weight transposes (LDS tiles); [168,232) combined el/er weights;
// [232,328) zero B-pad; [328,645) zero sbuf/tsum/cnt
__global__ __launch_bounds__(256) void prep(const float* __restrict__ proj_W,
    const float* __restrict__ short_W, const float* __restrict__ gat_W,
    const float* __restrict__ gat_al, const float* __restrict__ gat_ar,
    const float* __restrict__ sem_W1,
    ushort* btpl, ushort* btpd, ushort* btgl, ushort* btgd, ushort* btsm,
    int* __restrict__ zbuf){
  int b = blockIdx.x;
  if (b < 168){
    int t = b;   // 0..167
    const float* S; ushort* outb; int n0, k0, ldS=256, colbase;
    if (t < 160){
      int m = t >> 4, tt = t & 15;
      n0 = (tt & 3) * 64; k0 = (tt >> 2) * 64;
      switch(m){
        case 0: S=proj_W;        outb=btpl; colbase=0;   break;
        case 1: S=short_W;       outb=btpl; colbase=256; break;
        case 2: S=proj_W+65536;  outb=btpd; colbase=0;   break;
        case 3: S=short_W+65536; outb=btpd; colbase=256; break;
        case 4: S=gat_W;         outb=btgl; colbase=0;   break;
        case 5: S=gat_W+65536;   outb=btgl; colbase=256; break;
        case 6: S=gat_W+131072;  outb=btgl; colbase=512; break;
        case 7: S=gat_W;         outb=btgd; colbase=0;   break;
        case 8: S=gat_W+131072;  outb=btgd; colbase=256; break;
        default:S=gat_W+196608;  outb=btgd; colbase=512; break;
      }
    } else {
      int s = t - 160;
      n0 = (s & 1)*64; k0 = (s >> 1)*64; ldS = 128;
      S = sem_W1; outb = btsm; colbase = 0;
    }
    __shared__ float tile[64][65];
    int tr = threadIdx.x >> 6;
    int tc = threadIdx.x & 63;
    #pragma unroll
    for (int p=0;p<16;p++){
      int kr = p*4 + tr;
      tile[kr][tc] = S[(size_t)(k0+kr)*ldS + n0 + tc];
    }
    __syncthreads();
    #pragma unroll
    for (int p=0;p<16;p++){
      int nr = p*4 + tr;
      outb[(size_t)(colbase + n0 + nr)*256 + k0 + tc] = f2h(tile[tc][nr]);
    }
  } else if (b < 232){
    // combined attention weights: wl/wr[k,c] = sum_d W[k,h*32+d]*a[h,d]
    int idx = (b-168)*256 + threadIdx.x;   // 0..16383
    int side = idx >> 13;
    int r = idx & 8191;
    int c = r >> 8;                        // 0..31
    int k = r & 255;
    int h = c & 7, sel = c >> 3;
    int gi; const float* av;
    if (side==0){ // (W0,al0),(W1,al1),(W1,ar1),(W2,ar2)
      gi = (sel==0)?0:((sel==3)?2:1);
      av = (sel<=1)? gat_al : gat_ar;
    } else {      // (W0,ar0),(W2,al2),(W3,al3),(W3,ar3)
      gi = (sel==0)?0:((sel==1)?2:3);
      av = (sel==1||sel==2)? gat_al : gat_ar;
    }
    const float* wrow = gat_W + gi*65536 + (size_t)k*256 + h*32;
    const float* a = av + gi*256 + h*32;
    float s = 0.f;
    #pragma unroll
    for (int d=0; d<32; d++) s += wrow[d]*a[d];
    ushort* out = side ? btgd : btgl;
    out[(size_t)(768+c)*256 + k] = f2h(s);
  } else if (b < 328){
    int idx = (b-232)*256 + threadIdx.x;   // 0..24575 uints
    uint* pl = (uint*)(btgl + 800*256);
    uint* pd = (uint*)(btgd + 800*256);
    if (idx < 12288) pl[idx] = 0; else pd[idx-12288] = 0;
  } else {
    int idx = (b-328)*256 + threadIdx.x;
    if (idx < 81028) zbuf[idx] = 0;
  }
}

// fp16 GEMM, K=256, 128x128 tile, 4 waves, 16x16x32 MFMA.
// EPI: 1=proj (A staged from fp32 with inline cvt; store fp16 + bn col-stats; z==2 -> edge scatter),
//      2=gat (store fp16; col-block 6 -> packed fp32 el/er), 3=sem (tanh-dot only)
template<int EPI>
__global__ __launch_bounds__(256) void gemm16(
    const float* __restrict__ Af0, const float* __restrict__ Af1,
    const ushort* __restrict__ A0, const ushort* __restrict__ A1,
    const ushort* __restrict__ B0, const ushort* __restrict__ B1,
    ushort* __restrict__ C0, ushort* __restrict__ C1, int ldc, int M,
    float* __restrict__ sbuf,
    float* __restrict__ elr_l, float* __restrict__ elr_d,
    const float* __restrict__ b1v, const float* __restrict__ w2v,
    const int* s0, const int* s1, const int* s2, const int* s3,
    const int* d0, const int* d1, const int* d2, const int* d3,
    int* __restrict__ cnt, int* __restrict__ slots){
  const int z = blockIdx.z;
  if (EPI==1 && z==2){
    int bb = blockIdx.y*gridDim.x + blockIdx.x;       // 0..627
    int tid = bb*256 + (int)threadIdx.x;              // 0..160767
    if (tid < NE){
      #pragma unroll
      for (int g=0; g<4; g++){
        const int* src = (g==0)?s0:(g==1)?s1:(g==2)?s2:s3;
        const int* dst = (g==0)?d0:(g==1)?d1:(g==2)?d2:d3;
        int d = dst[tid];
        int p = atomicAdd(&cnt[g*NN + d], 1);
        slots[(size_t)(g*NN + d)*SLOT + p] = src[tid];
      }
    }
    return;
  }
  const float* Af = z ? Af1 : Af0;
  const ushort* A = z ? A1 : A0;
  const ushort* Bt = z ? B1 : B0;
  ushort* C = z ? C1 : C0;
  __shared__ ushort sm[16384];
  char* smc = (char*)sm;
  const int tid = threadIdx.x;
  const int lane = tid & 63, wid = tid >> 6;
  const int wr = wid >> 1, wc = wid & 1;
  const int fr = lane & 15, fq = lane >> 4;
  const int brow = blockIdx.y*128, bcol = blockIdx.x*128;
  f32x4 acc[4][4];
  #pragma unroll
  for (int i=0;i<4;i++)
    #pragma unroll
    for (int j=0;j<4;j++) acc[i][j] = (f32x4){0.f,0.f,0.f,0.f};

  for (int k0 = 0; k0 < 256; k0 += 64){
    __syncthreads();
    #pragma unroll
    for (int cc = 0; cc < 8; cc++){
      int c = wid*8 + cc;
      int ch = c & 15;
      int rel = ch*1024 + lane*16;
      int row = rel >> 7;
      int colb = rel & 127;
      int scb = colb ^ ((row & 7) << 4);
      if (c < 16){
        int gr = brow + row; gr = (gr < M) ? gr : (M-1);
        if (EPI==1){
          // reg-stage A from fp32 with inline fp16 cvt; swizzled ds_write
          const float* srcf = Af + (size_t)gr*256 + k0 + (colb>>1);
          float4 v0 = *(const float4*)(srcf);
          float4 v1 = *(const float4*)(srcf + 4);
          f16x8 hv;
          hv[0]=(f16)v0.x; hv[1]=(f16)v0.y; hv[2]=(f16)v0.z; hv[3]=(f16)v0.w;
          hv[4]=(f16)v1.x; hv[5]=(f16)v1.y; hv[6]=(f16)v1.z; hv[7]=(f16)v1.w;
          *(f16x8*)(smc + (rel & ~127) + scb) = hv;
        } else {
          const char* src = (const char*)A + (size_t)gr*512 + k0*2 + scb;
          gload_lds16(src, smc + ch*1024);
        }
      } else {
        const char* src = (const char*)Bt + (size_t)(bcol + row)*512 + k0*2 + scb;
        gload_lds16(src, smc + 16384 + ch*1024);
      }
    }
    __syncthreads();
    #pragma unroll
    for (int ks = 0; ks < 2; ks++){
      f16x8 af[4], bfr[4];
      #pragma unroll
      for (int i=0;i<4;i++){
        int r = wr*64 + i*16 + fr;
        int koff = ks*32 + fq*8;
        int aoff = ((r<<7) + koff*2) ^ ((r&7)<<4);
        af[i] = *(const f16x8*)(smc + aoff);
        int n = wc*64 + i*16 + fr;
        int boff = ((n<<7) + koff*2) ^ ((n&7)<<4);
        bfr[i] = *(const f16x8*)(smc + 16384 + boff);
      }
      #pragma unroll
      for (int i=0;i<4;i++)
        #pragma unroll
        for (int j=0;j<4;j++)
          acc[i][j] = __builtin_amdgcn_mfma_f32_16x16x32_f16(af[i], bfr[j], acc[i][j], 0,0,0);
    }
  }

  if (EPI==1 || (EPI==2 && bcol < 768)){
    #pragma unroll
    for (int i=0;i<4;i++){
      #pragma unroll
      for (int e=0;e<4;e++){
        int gr = brow + wr*64 + i*16 + fq*4 + e;
        if (gr < M){
          #pragma unroll
          for (int j=0;j<4;j++)
            C[(size_t)gr*ldc + bcol + wc*64 + j*16 + fr] = f2h(acc[i][j][e]);
        }
      }
    }
  }

  if (EPI==2 && bcol >= 768 && wc == 0){
    float* elr = z ? elr_d : elr_l;
    #pragma unroll
    for (int i=0;i<4;i++){
      #pragma unroll
      for (int e=0;e<4;e++){
        int gr = brow + wr*64 + i*16 + fq*4 + e;
        if (gr < M){
          elr[(size_t)gr*32 + fr]      = acc[i][0][e];
          elr[(size_t)gr*32 + 16 + fr] = acc[i][1][e];
        }
      }
    }
  }

  if (EPI==1 && bcol < 256){
    float* gsum = sbuf + z*512;
    float* gsq  = gsum + 256;
    #pragma unroll
    for (int j=0;j<4;j++){
      float s=0.f, q=0.f;
      #pragma unroll
      for (int i=0;i<4;i++)
        #pragma unroll
        for (int e=0;e<4;e++){
          int gr = brow + wr*64 + i*16 + fq*4 + e;
          if (gr < M){ float v = acc[i][j][e]; s += v; q += v*v; }
        }
      s += __shfl_xor(s,16); s += __shfl_xor(s,32);
      q += __shfl_xor(q,16); q += __shfl_xor(q,32);
      if (fq==0){
        int gc = bcol + wc*64 + j*16 + fr;
        atomicAdd(&gsum[gc], s);
        atomicAdd(&gsq[gc], q);
      }
    }
  }

  if (EPI==3){
    float b1c[4], w2c[4];
    #pragma unroll
    for (int j=0;j<4;j++){
      int col = wc*64 + j*16 + fr;
      b1c[j] = b1v[col]; w2c[j] = w2v[col];
    }
    int segA = brow/20000;
    int bound = (segA+1)*20000;
    float t0=0.f, t1=0.f;
    #pragma unroll
    for (int i=0;i<4;i++){
      #pragma unroll
      for (int e=0;e<4;e++){
        int gr = brow + wr*64 + i*16 + fq*4 + e;
        float rs = 0.f;
        #pragma unroll
        for (int j=0;j<4;j++){
          float x = acc[i][j][e] + b1c[j];
          float ex = __expf(2.f*x);
          rs += (1.f - 2.f/(ex+1.f))*w2c[j];
        }
        if (gr < bound) t0 += rs; else t1 += rs;
      }
    }
    #pragma unroll
    for (int off=32; off>0; off>>=1){ t0 += __shfl_xor(t0,off); t1 += __shfl_xor(t1,off); }
    if (lane==0){
      atomicAdd(&sbuf[segA], t0);
      if (brow + 127 >= bound) atomicAdd(&sbuf[segA+1], t1);
    }
  }
}

// BN-apply with inline stats finalization; grid (5000,2)
__global__ __launch_bounds__(256) void proj_apply2(const ushort* __restrict__ PS_l,
    const ushort* __restrict__ PS_d, const float* __restrict__ sbuf,
    const float* __restrict__ gg, const float* __restrict__ bb,
    const float* __restrict__ short_b, ushort* __restrict__ out_l, ushort* __restrict__ out_d){
  int y = blockIdx.y;
  const ushort* PS = y ? PS_d : PS_l;
  ushort* out = y ? out_d : out_l;
  const float* gsum = sbuf + y*512;
  const float* gsq  = gsum + 256;
  const float* sb = short_b + y*256;
  long idx = (long)blockIdx.x*256 + threadIdx.x;
  long r = idx>>6; int c4 = (int)(idx&63)<<2;
  ushort4 pu = *(const ushort4*)(PS + r*512 + c4);
  ushort4 su = *(const ushort4*)(PS + r*512 + 256 + c4);
  float pv[4] = {h2f(pu.x),h2f(pu.y),h2f(pu.z),h2f(pu.w)};
  float sv[4] = {h2f(su.x),h2f(su.y),h2f(su.z),h2f(su.w)};
  ushort o[4];
  #pragma unroll
  for (int k=0;k<4;k++){
    int c = c4+k;
    float m = gsum[c]*(1.f/NN);
    float va = gsq[c]*(1.f/NN) - m*m;
    float ri = rsqrtf(va + 1e-5f);
    float yv = (pv[k]-m)*ri*gg[c] + bb[c];
    o[k] = f2h(leakyf(yv,0.01f) + sv[k] + sb[c]);
  }
  ushort4 ov; ov.x=o[0]; ov.y=o[1]; ov.z=o[2]; ov.w=o[3];
  *(ushort4*)(out + r*256 + c4) = ov;
}

// fused GAT: shift-free softmax + aggregation; grid (5000,4); packed fp32 el/er
__global__ __launch_bounds__(256) void gat_fused(const int* __restrict__ cnt,
    const int* __restrict__ slots, const float* __restrict__ elr_l,
    const float* __restrict__ elr_d, const ushort* __restrict__ fc_l,
    const ushort* __restrict__ fc_d, ushort* __restrict__ sems){
  const int g = blockIdx.y;
  const int n = blockIdx.x*4 + (threadIdx.x>>6);
  const int lane = threadIdx.x & 63;
  const int co[4]    = {0,256,256,512};
  const int semo[4]  = {40000,0,20000,60000};
  const int eloA[4]  = {0,8,8,16};
  const int eroA[4]  = {0,16,24,24};
  const float* elb = (g<2) ? elr_l : elr_d;
  const float* erb = (g==1||g==2) ? elr_l : elr_d;
  const int eloff = eloA[g], eroff = eroA[g];
  const ushort* F = (g<2) ? fc_l : fc_d;
  const int coloff = co[g];
  const int j = lane>>3, h = lane&7, hc = lane>>3;
  const int e1 = cnt[g*NN + n];
  const long sb = (long)(g*NN + n)*SLOT;
  const float ern = erb[(size_t)n*32 + eroff + h];
  float ssum = 0.f;
  float4 acc = make_float4(0.f,0.f,0.f,0.f);

  for (int base = 0; base < e1; base += 8){
    int idx = base + j;
    bool valid = idx < e1;
    int src = valid ? slots[sb + idx] : 0;
    float p = valid ? __expf(leakyf(elb[(size_t)src*32 + eloff + h] + ern, 0.2f)) : 0.f;
    ssum += p;
    #pragma unroll
    for (int e=0;e<8;e++){
      float w = __shfl(p, e*8 + hc);
      int s = __shfl(src, e*8);
      ushort4 fu = *(const ushort4*)(F + (size_t)s*768 + coloff + lane*4);
      acc.x = fmaf(w,h2f(fu.x),acc.x); acc.y = fmaf(w,h2f(fu.y),acc.y);
      acc.z = fmaf(w,h2f(fu.z),acc.z); acc.w = fmaf(w,h2f(fu.w),acc.w);
    }
  }
  ssum += __shfl_xor(ssum,8); ssum += __shfl_xor(ssum,16); ssum += __shfl_xor(ssum,32);
  float rd = 1.f/fmaxf(__shfl(ssum, hc), 1e-9f);
  ushort4 o;
  o.x = f2h(leakyf(acc.x*rd, 0.01f)); o.y = f2h(leakyf(acc.y*rd, 0.01f));
  o.z = f2h(leakyf(acc.z*rd, 0.01f)); o.w = f2h(leakyf(acc.w*rd, 0.01f));
  *(ushort4*)(sems + (size_t)(semo[g]+n)*256 + lane*4) = o;
}

// beta inline + combine; fp32 outputs (nontemporal) + fp16 gather copies; grid 5000
__global__ __launch_bounds__(256) void sem_combine(const ushort* __restrict__ sems,
    const float* __restrict__ tsum, float* __restrict__ lemb, float* __restrict__ demb,
    ushort* __restrict__ lemb16, ushort* __restrict__ demb16){
  float wl0 = tsum[0]*(1.f/20000.f), wl1 = tsum[1]*(1.f/20000.f);
  float m = fmaxf(wl0,wl1);
  float ea = __expf(wl0-m), eb = __expf(wl1-m);
  float b0 = ea/(ea+eb), b1 = eb/(ea+eb);
  float wd0 = tsum[2]*(1.f/20000.f), wd1 = tsum[3]*(1.f/20000.f);
  m = fmaxf(wd0,wd1);
  ea = __expf(wd0-m); eb = __expf(wd1-m);
  float b2 = ea/(ea+eb), b3 = eb/(ea+eb);

  long idx = (long)blockIdx.x*256 + threadIdx.x;
  long r = idx>>6; int c4 = (int)(idx&63)<<2;
  ushort4 v1 = *(const ushort4*)(sems + (r          )*256 + c4);
  ushort4 v2 = *(const ushort4*)(sems + (r + 20000L )*256 + c4);
  ushort4 v0 = *(const ushort4*)(sems + (r + 40000L )*256 + c4);
  ushort4 v3 = *(const ushort4*)(sems + (r + 60000L )*256 + c4);
  f32x4 lo, dd;
  lo[0] = b0*h2f(v1.x) + b1*h2f(v2.x); dd[0] = b2*h2f(v0.x) + b3*h2f(v3.x);
  lo[1] = b0*h2f(v1.y) + b1*h2f(v2.y); dd[1] = b2*h2f(v0.y) + b3*h2f(v3.y);
  lo[2] = b0*h2f(v1.z) + b1*h2f(v2.z); dd[2] = b2*h2f(v0.z) + b3*h2f(v3.z);
  lo[3] = b0*h2f(v1.w) + b1*h2f(v2.w); dd[3] = b2*h2f(v0.w) + b3*h2f(v3.w);
  nts4(lemb + r*256 + c4, lo);
  nts4(demb + r*256 + c4, dd);
  ushort4 lh, dh;
  lh.x=f2h(lo[0]); lh.y=f2h(lo[1]); lh.z=f2h(lo[2]); lh.w=f2h(lo[3]);
  dh.x=f2h(dd[0]); dh.y=f2h(dd[1]); dh.z=f2h(dd[2]); dh.w=f2h(dd[3]);
  *(ushort4*)(lemb16 + r*256 + c4) = lh;
  *(ushort4*)(demb16 + r*256 + c4) = dh;
}

// pos+neg in one launch; 16B/lane fp16 gathers, 32B/thread nt stores; grid 40000
__global__ __launch_bounds__(256) void edge_mul2(const int* __restrict__ ps, const int* __restrict__ pd,
    const int* __restrict__ ns, const int* __restrict__ nd,
    const ushort* __restrict__ lemb16, const ushort* __restrict__ demb16,
    float* __restrict__ pos, float* __restrict__ neg){
  long idx = (long)blockIdx.x*256 + threadIdx.x;
  const long H = (long)NE*32;
  const int *es, *ed; float* out; long t;
  if (idx < H){ es=ps; ed=pd; out=pos; t=idx; }
  else { es=ns; ed=nd; out=neg; t=idx-H; }
  long i = t>>5; int jj = (int)(t&31);
  int s = es[i], d = ed[i];
  f16x8 a = *(const f16x8*)(lemb16 + (size_t)s*256 + (size_t)jj*8);
  f16x8 b = *(const f16x8*)(demb16 + (size_t)d*256 + (size_t)jj*8);
  f32x4 o0, o1;
  o0[0]=(float)a[0]*(float)b[0]; o0[1]=(float)a[1]*(float)b[1];
  o0[2]=(float)a[2]*(float)b[2]; o0[3]=(float)a[3]*(float)b[3];
  o1[0]=(float)a[4]*(float)b[4]; o1[1]=(float)a[5]*(float)b[5];
  o1[2]=(float)a[6]*(float)b[6]; o1[3]=(float)a[7]*(float)b[7];
  float* op = out + (size_t)i*256 + (size_t)jj*8;
  nts4(op, o0);
  nts4(op+4, o1);
}

extern "C" void kernel_launch(void* const* d_in, const int* in_sizes, int n_in,
                              void* d_out, int out_size, void* d_ws, size_t ws_size,
                              hipStream_t stream){
  const float* x_lnc  = (const float*)d_in[0];
  const float* x_dis  = (const float*)d_in[1];
  const float* proj_W = (const float*)d_in[2];
  const float* bn_g   = (const float*)d_in[3];
  const float* bn_b   = (const float*)d_in[4];
  const float* short_W= (const float*)d_in[5];
  const float* short_b= (const float*)d_in[6];
  const float* gat_W  = (const float*)d_in[7];
  const float* gat_al = (const float*)d_in[8];
  const float* gat_ar = (const float*)d_in[9];
  const float* sem_W1 = (const float*)d_in[10];
  const float* sem_b1 = (const float*)d_in[11];
  const float* sem_w2 = (const float*)d_in[12];
  const int* g_src[4] = {(const int*)d_in[13],(const int*)d_in[15],(const int*)d_in[17],(const int*)d_in[19]};
  const int* g_dst[4] = {(const int*)d_in[14],(const int*)d_in[16],(const int*)d_in[18],(const int*)d_in[20]};
  const int* pos_src = (const int*)d_in[21];
  const int* pos_dst = (const int*)d_in[22];
  const int* neg_src = (const int*)d_in[23];
  const int* neg_dst = (const int*)d_in[24];

  const long LEMB = (long)NN*256;
  const long EOUT = (long)NE*256;

  float* outf = (float*)d_out;
  float* pos  = outf;
  float* negr = outf + EOUT;
  float* lemb = outf + 2*EOUT;
  float* demb = lemb + LEMB;

  // fp16 scratch in d_out neg region (dead before edge_mul2 writes it):
  ushort* PS_l = (ushort*)negr;            // [20000][512] fp16
  ushort* PS_d = PS_l + 10240000;
  ushort* fc_l = (ushort*)negr;            // [20000][768] fp16 (after PS dead)
  ushort* fc_d = fc_l + 15360000;

  float* ws   = (float*)d_ws;
  float* sbuf = ws;                            // 1024 (zeroed by prep)
  float* tsum = ws + 1024;                     // 4   (zeroed)
  int*   cnt  = (int*)(ws + 1028);             // 80000 (zeroed) -> fill span 81028 words
  float* elr_l = ws + 81028;                   // 640000 (packed [n][32] fp32)
  float* elr_d = elr_l + 640000;               // 640000
  int*   slots  = (int*)(elr_d + 640000);      // 3,200,000
  ushort* axl  = (ushort*)(slots + 3200000);   // 5,120,000
  ushort* axd  = axl + 5120000;
  ushort* sems = axd + 5120000;                // 20,480,000
  ushort* lemb16 = sems + 20480000;            // 5,120,000
  ushort* demb16 = lemb16 + 5120000;
  ushort* btpl = demb16 + 5120000;             // 512*256
  ushort* btpd = btpl + 131072;                // 512*256
  ushort* btgl = btpd + 131072;                // 896*256
  ushort* btgd = btgl + 229376;                // 896*256
  ushort* btsm = btgd + 229376;                // 128*256

  prep<<<645,256,0,stream>>>(proj_W, short_W, gat_W, gat_al, gat_ar,
                             sem_W1, btpl, btpd, btgl, btgd, btsm, (int*)ws);

  // stage 1: proj+shortcut GEMM from fp32 A (fused bn stats; z=2 overlaps the edge scatter)
  gemm16<1><<<dim3(4,157,3),256,0,stream>>>(x_lnc, x_dis, nullptr, nullptr,
      btpl, btpd, PS_l, PS_d, 512, NN,
      sbuf, nullptr, nullptr, nullptr, nullptr,
      g_src[0],g_src[1],g_src[2],g_src[3], g_dst[0],g_dst[1],g_dst[2],g_dst[3],
      cnt, slots);
  proj_apply2<<<dim3(5000,2),256,0,stream>>>(PS_l, PS_d, sbuf, bn_g, bn_b, short_b, axl, axd);

  // stage 2: GAT fc GEMM; col-block 6 emits packed fp32 el/er
  gemm16<2><<<dim3(7,157,2),256,0,stream>>>(nullptr, nullptr, axl, axd,
      btgl, btgd, fc_l, fc_d, 768, NN,
      nullptr, elr_l, elr_d, nullptr, nullptr,
      nullptr,nullptr,nullptr,nullptr, nullptr,nullptr,nullptr,nullptr, nullptr,nullptr);

  // fused GAT (shift-free softmax + aggregate), writes stacked fp16 [e1;e2;e0;e3]
  gat_fused<<<dim3(5000,4),256,0,stream>>>(cnt, slots, elr_l, elr_d, fc_l, fc_d, sems);

  // semantic attention GEMM with fused tanh-dot epilogue
  gemm16<3><<<dim3(1,625,1),256,0,stream>>>(nullptr, nullptr, sems, nullptr,
      btsm, nullptr, nullptr, nullptr, 128, 80000,
      tsum, nullptr, nullptr, sem_b1, sem_w2,
      nullptr,nullptr,nullptr,nullptr, nullptr,nullptr,nullptr,nullptr, nullptr,nullptr);

  // beta (inline) + combine -> fp32 outputs (nt) + fp16 gather copies
  sem_combine<<<5000,256,0,stream>>>(sems, tsum, lemb, demb, lemb16, demb16);

  // link outputs (nt stores)
  edge_mul2<<<40000,256,0,stream>>>(pos_src, pos_dst, neg_src, neg_dst, lemb16, demb16, pos, negr);
}

// Round 10
// 351.321 us; speedup vs baseline: 1.1116x; 1.1116x over previous
//
#include <hip/hip_runtime.h>
#include <math.h>

#define NN 20000
#define NE 160000
#define SLOT 40

typedef _Float16 f16;
typedef __attribute__((ext_vector_type(8))) _Float16 f16x8;
typedef __attribute__((ext_vector_type(4))) float f32x4;

__device__ __forceinline__ float leakyf(float x, float s){ return x >= 0.f ? x : s*x; }
__device__ __forceinline__ ushort f2h(float x){ f16 h = (f16)x; ushort u; __builtin_memcpy(&u,&h,2); return u; }
__device__ __forceinline__ float h2f(ushort u){ f16 h; __builtin_memcpy(&h,&u,2); return (float)h; }

__device__ __forceinline__ void gload_lds16(const void* g, void* l){
  __builtin_amdgcn_global_load_lds((const __attribute__((address_space(1))) uint*)g,
                                   (__attribute__((address_space(3))) uint*)l, 16, 0, 0);
}
__device__ __forceinline__ void nts4(float* p, f32x4 v){
  __builtin_nontemporal_store(v, (f32x4*)p);
}

// prep blocks: [0,10000) conv_x; [10000,10168) weight transposes (LDS tiles);
// [10168,10232) combined el/er weights; [10232,10328) zero B-pad; [10328,10645) zero zbuf
__global__ __launch_bounds__(256) void prep(const float* __restrict__ x_lnc,
    const float* __restrict__ x_dis, const float* __restrict__ proj_W,
    const float* __restrict__ short_W, const float* __restrict__ gat_W,
    const float* __restrict__ gat_al, const float* __restrict__ gat_ar,
    const float* __restrict__ sem_W1,
    ushort* __restrict__ xhl, ushort* __restrict__ xhd,
    ushort* btpl, ushort* btpd, ushort* btgl, ushort* btgd, ushort* btsm,
    int* __restrict__ zbuf){
  int b = blockIdx.x;
  if (b < 10000){
    const float* in = (b >= 5000) ? x_dis : x_lnc;
    ushort* out = (b >= 5000) ? xhd : xhl;
    long idx = (long)(b % 5000)*256 + threadIdx.x;
    long r = idx>>6; int c4 = (int)(idx&63)<<2;
    float4 v = *(const float4*)(in + r*256 + c4);
    ushort4 o; o.x=f2h(v.x); o.y=f2h(v.y); o.z=f2h(v.z); o.w=f2h(v.w);
    *(ushort4*)(out + r*256 + c4) = o;
  } else if (b < 10168){
    int t = b - 10000;   // 0..167
    const float* S; ushort* outb; int n0, k0, ldS=256, colbase;
    if (t < 160){
      int m = t >> 4, tt = t & 15;
      n0 = (tt & 3) * 64; k0 = (tt >> 2) * 64;
      switch(m){
        case 0: S=proj_W;        outb=btpl; colbase=0;   break;
        case 1: S=short_W;       outb=btpl; colbase=256; break;
        case 2: S=proj_W+65536;  outb=btpd; colbase=0;   break;
        case 3: S=short_W+65536; outb=btpd; colbase=256; break;
        case 4: S=gat_W;         outb=btgl; colbase=0;   break;
        case 5: S=gat_W+65536;   outb=btgl; colbase=256; break;
        case 6: S=gat_W+131072;  outb=btgl; colbase=512; break;
        case 7: S=gat_W;         outb=btgd; colbase=0;   break;
        case 8: S=gat_W+131072;  outb=btgd; colbase=256; break;
        default:S=gat_W+196608;  outb=btgd; colbase=512; break;
      }
    } else {
      int s = t - 160;
      n0 = (s & 1)*64; k0 = (s >> 1)*64; ldS = 128;
      S = sem_W1; outb = btsm; colbase = 0;
    }
    __shared__ float tile[64][65];
    int tr = threadIdx.x >> 6;
    int tc = threadIdx.x & 63;
    #pragma unroll
    for (int p=0;p<16;p++){
      int kr = p*4 + tr;
      tile[kr][tc] = S[(size_t)(k0+kr)*ldS + n0 + tc];
    }
    __syncthreads();
    #pragma unroll
    for (int p=0;p<16;p++){
      int nr = p*4 + tr;
      outb[(size_t)(colbase + n0 + nr)*256 + k0 + tc] = f2h(tile[tc][nr]);
    }
  } else if (b < 10232){
    // combined attention weights: wl/wr[k,c] = sum_d W[k,h*32+d]*a[h,d]
    int idx = (b-10168)*256 + threadIdx.x;   // 0..16383
    int side = idx >> 13;
    int r = idx & 8191;
    int c = r >> 8;                          // 0..31
    int k = r & 255;
    int h = c & 7, sel = c >> 3;
    int gi; const float* av;
    if (side==0){ // (W0,al0),(W1,al1),(W1,ar1),(W2,ar2)
      gi = (sel==0)?0:((sel==3)?2:1);
      av = (sel<=1)? gat_al : gat_ar;
    } else {      // (W0,ar0),(W2,al2),(W3,al3),(W3,ar3)
      gi = (sel==0)?0:((sel==1)?2:3);
      av = (sel==1||sel==2)? gat_al : gat_ar;
    }
    const float* wrow = gat_W + gi*65536 + (size_t)k*256 + h*32;
    const float* a = av + gi*256 + h*32;
    float s = 0.f;
    #pragma unroll
    for (int d=0; d<32; d++) s += wrow[d]*a[d];
    ushort* out = side ? btgd : btgl;
    out[(size_t)(768+c)*256 + k] = f2h(s);
  } else if (b < 10328){
    int idx = (b-10232)*256 + threadIdx.x;   // 0..24575 uints
    uint* pl = (uint*)(btgl + 800*256);
    uint* pd = (uint*)(btgd + 800*256);
    if (idx < 12288) pl[idx] = 0; else pd[idx-12288] = 0;
  } else {
    int idx = (b-10328)*256 + threadIdx.x;
    if (idx < 81028) zbuf[idx] = 0;
  }
}

// fp16 GEMM, K=256, 128x128 tile, 4 waves, 16x16x32 MFMA.
// EPI: 1=proj (store fp16 + bn col-stats; z==2 -> edge scatter instead),
//      2=gat (store fp16; col-block 6 -> packed fp32 el/er), 3=sem (tanh-dot only)
template<int EPI>
__global__ __launch_bounds__(256) void gemm16(
    const ushort* __restrict__ A0, const ushort* __restrict__ A1,
    const ushort* __restrict__ B0, const ushort* __restrict__ B1,
    ushort* __restrict__ C0, ushort* __restrict__ C1, int ldc, int M,
    float* __restrict__ sbuf,
    float* __restrict__ elr_l, float* __restrict__ elr_d,
    const float* __restrict__ b1v, const float* __restrict__ w2v,
    const int* s0, const int* s1, const int* s2, const int* s3,
    const int* d0, const int* d1, const int* d2, const int* d3,
    int* __restrict__ cnt, int* __restrict__ slots){
  const int z = blockIdx.z;
  if (EPI==1 && z==2){
    int bb = blockIdx.y*gridDim.x + blockIdx.x;       // 0..627
    int tid = bb*256 + (int)threadIdx.x;              // 0..160767
    if (tid < NE){
      #pragma unroll
      for (int g=0; g<4; g++){
        const int* src = (g==0)?s0:(g==1)?s1:(g==2)?s2:s3;
        const int* dst = (g==0)?d0:(g==1)?d1:(g==2)?d2:d3;
        int d = dst[tid];
        int p = atomicAdd(&cnt[g*NN + d], 1);
        slots[(size_t)(g*NN + d)*SLOT + p] = src[tid];
      }
    }
    return;
  }
  const ushort* A = z ? A1 : A0;
  const ushort* Bt = z ? B1 : B0;
  ushort* C = z ? C1 : C0;
  __shared__ ushort sm[16384];
  char* smc = (char*)sm;
  const int tid = threadIdx.x;
  const int lane = tid & 63, wid = tid >> 6;
  const int wr = wid >> 1, wc = wid & 1;
  const int fr = lane & 15, fq = lane >> 4;
  const int brow = blockIdx.y*128, bcol = blockIdx.x*128;
  f32x4 acc[4][4];
  #pragma unroll
  for (int i=0;i<4;i++)
    #pragma unroll
    for (int j=0;j<4;j++) acc[i][j] = (f32x4){0.f,0.f,0.f,0.f};

  for (int k0 = 0; k0 < 256; k0 += 64){
    __syncthreads();
    #pragma unroll
    for (int cc = 0; cc < 8; cc++){
      int c = wid*8 + cc;
      int ch = c & 15;
      int rel = ch*1024 + lane*16;
      int row = rel >> 7;
      int scb = (rel & 127) ^ ((row & 7) << 4);
      const char* src;
      if (c < 16){
        int gr = brow + row; gr = (gr < M) ? gr : (M-1);
        src = (const char*)A + (size_t)gr*512 + k0*2 + scb;
      } else {
        src = (const char*)Bt + (size_t)(bcol + row)*512 + k0*2 + scb;
      }
      gload_lds16(src, smc + ((c<16)?0:16384) + ch*1024);
    }
    __syncthreads();
    #pragma unroll
    for (int ks = 0; ks < 2; ks++){
      f16x8 af[4], bfr[4];
      #pragma unroll
      for (int i=0;i<4;i++){
        int r = wr*64 + i*16 + fr;
        int koff = ks*32 + fq*8;
        int aoff = ((r<<7) + koff*2) ^ ((r&7)<<4);
        af[i] = *(const f16x8*)(smc + aoff);
        int n = wc*64 + i*16 + fr;
        int boff = ((n<<7) + koff*2) ^ ((n&7)<<4);
        bfr[i] = *(const f16x8*)(smc + 16384 + boff);
      }
      #pragma unroll
      for (int i=0;i<4;i++)
        #pragma unroll
        for (int j=0;j<4;j++)
          acc[i][j] = __builtin_amdgcn_mfma_f32_16x16x32_f16(af[i], bfr[j], acc[i][j], 0,0,0);
    }
  }

  if (EPI==1 || (EPI==2 && bcol < 768)){
    #pragma unroll
    for (int i=0;i<4;i++){
      #pragma unroll
      for (int e=0;e<4;e++){
        int gr = brow + wr*64 + i*16 + fq*4 + e;
        if (gr < M){
          #pragma unroll
          for (int j=0;j<4;j++)
            C[(size_t)gr*ldc + bcol + wc*64 + j*16 + fr] = f2h(acc[i][j][e]);
        }
      }
    }
  }

  if (EPI==2 && bcol >= 768 && wc == 0){
    float* elr = z ? elr_d : elr_l;
    #pragma unroll
    for (int i=0;i<4;i++){
      #pragma unroll
      for (int e=0;e<4;e++){
        int gr = brow + wr*64 + i*16 + fq*4 + e;
        if (gr < M){
          elr[(size_t)gr*32 + fr]      = acc[i][0][e];
          elr[(size_t)gr*32 + 16 + fr] = acc[i][1][e];
        }
      }
    }
  }

  if (EPI==1 && bcol < 256){
    float* gsum = sbuf + z*512;
    float* gsq  = gsum + 256;
    #pragma unroll
    for (int j=0;j<4;j++){
      float s=0.f, q=0.f;
      #pragma unroll
      for (int i=0;i<4;i++)
        #pragma unroll
        for (int e=0;e<4;e++){
          int gr = brow + wr*64 + i*16 + fq*4 + e;
          if (gr < M){ float v = acc[i][j][e]; s += v; q += v*v; }
        }
      s += __shfl_xor(s,16); s += __shfl_xor(s,32);
      q += __shfl_xor(q,16); q += __shfl_xor(q,32);
      if (fq==0){
        int gc = bcol + wc*64 + j*16 + fr;
        atomicAdd(&gsum[gc], s);
        atomicAdd(&gsq[gc], q);
      }
    }
  }

  if (EPI==3){
    float b1c[4], w2c[4];
    #pragma unroll
    for (int j=0;j<4;j++){
      int col = wc*64 + j*16 + fr;
      b1c[j] = b1v[col]; w2c[j] = w2v[col];
    }
    int segA = brow/20000;
    int bound = (segA+1)*20000;
    float t0=0.f, t1=0.f;
    #pragma unroll
    for (int i=0;i<4;i++){
      #pragma unroll
      for (int e=0;e<4;e++){
        int gr = brow + wr*64 + i*16 + fq*4 + e;
        float rs = 0.f;
        #pragma unroll
        for (int j=0;j<4;j++){
          float x = acc[i][j][e] + b1c[j];
          float ex = __expf(2.f*x);
          rs += (1.f - 2.f/(ex+1.f))*w2c[j];
        }
        if (gr < bound) t0 += rs; else t1 += rs;
      }
    }
    #pragma unroll
    for (int off=32; off>0; off>>=1){ t0 += __shfl_xor(t0,off); t1 += __shfl_xor(t1,off); }
    if (lane==0){
      atomicAdd(&sbuf[segA], t0);
      if (brow + 127 >= bound) atomicAdd(&sbuf[segA+1], t1);
    }
  }
}

// BN-apply with inline stats finalization; grid (5000,2)
__global__ __launch_bounds__(256) void proj_apply2(const ushort* __restrict__ PS_l,
    const ushort* __restrict__ PS_d, const float* __restrict__ sbuf,
    const float* __restrict__ gg, const float* __restrict__ bb,
    const float* __restrict__ short_b, ushort* __restrict__ out_l, ushort* __restrict__ out_d){
  int y = blockIdx.y;
  const ushort* PS = y ? PS_d : PS_l;
  ushort* out = y ? out_d : out_l;
  const float* gsum = sbuf + y*512;
  const float* gsq  = gsum + 256;
  const float* sb = short_b + y*256;
  long idx = (long)blockIdx.x*256 + threadIdx.x;
  long r = idx>>6; int c4 = (int)(idx&63)<<2;
  ushort4 pu = *(const ushort4*)(PS + r*512 + c4);
  ushort4 su = *(const ushort4*)(PS + r*512 + 256 + c4);
  float pv[4] = {h2f(pu.x),h2f(pu.y),h2f(pu.z),h2f(pu.w)};
  float sv[4] = {h2f(su.x),h2f(su.y),h2f(su.z),h2f(su.w)};
  ushort o[4];
  #pragma unroll
  for (int k=0;k<4;k++){
    int c = c4+k;
    float m = gsum[c]*(1.f/NN);
    float va = gsq[c]*(1.f/NN) - m*m;
    float ri = rsqrtf(va + 1e-5f);
    float yv = (pv[k]-m)*ri*gg[c] + bb[c];
    o[k] = f2h(leakyf(yv,0.01f) + sv[k] + sb[c]);
  }
  ushort4 ov; ov.x=o[0]; ov.y=o[1]; ov.z=o[2]; ov.w=o[3];
  *(ushort4*)(out + r*256 + c4) = ov;
}

// fused GAT: shift-free softmax + aggregation; grid (5000,4); packed fp32 el/er
__global__ __launch_bounds__(256) void gat_fused(const int* __restrict__ cnt,
    const int* __restrict__ slots, const float* __restrict__ elr_l,
    const float* __restrict__ elr_d, const ushort* __restrict__ fc_l,
    const ushort* __restrict__ fc_d, ushort* __restrict__ sems){
  const int g = blockIdx.y;
  const int n = blockIdx.x*4 + (threadIdx.x>>6);
  const int lane = threadIdx.x & 63;
  const int co[4]    = {0,256,256,512};
  const int semo[4]  = {40000,0,20000,60000};
  const int eloA[4]  = {0,8,8,16};
  const int eroA[4]  = {0,16,24,24};
  const float* elb = (g<2) ? elr_l : elr_d;
  const float* erb = (g==1||g==2) ? elr_l : elr_d;
  const int eloff = eloA[g], eroff = eroA[g];
  const ushort* F = (g<2) ? fc_l : fc_d;
  const int coloff = co[g];
  const int j = lane>>3, h = lane&7, hc = lane>>3;
  const int e1 = cnt[g*NN + n];
  const long sb = (long)(g*NN + n)*SLOT;
  const float ern = erb[(size_t)n*32 + eroff + h];
  float ssum = 0.f;
  float4 acc = make_float4(0.f,0.f,0.f,0.f);

  for (int base = 0; base < e1; base += 8){
    int idx = base + j;
    bool valid = idx < e1;
    int src = valid ? slots[sb + idx] : 0;
    float p = valid ? __expf(leakyf(elb[(size_t)src*32 + eloff + h] + ern, 0.2f)) : 0.f;
    ssum += p;
    #pragma unroll
    for (int e=0;e<8;e++){
      float w = __shfl(p, e*8 + hc);
      int s = __shfl(src, e*8);
      ushort4 fu = *(const ushort4*)(F + (size_t)s*768 + coloff + lane*4);
      acc.x = fmaf(w,h2f(fu.x),acc.x); acc.y = fmaf(w,h2f(fu.y),acc.y);
      acc.z = fmaf(w,h2f(fu.z),acc.z); acc.w = fmaf(w,h2f(fu.w),acc.w);
    }
  }
  ssum += __shfl_xor(ssum,8); ssum += __shfl_xor(ssum,16); ssum += __shfl_xor(ssum,32);
  float rd = 1.f/fmaxf(__shfl(ssum, hc), 1e-9f);
  ushort4 o;
  o.x = f2h(leakyf(acc.x*rd, 0.01f)); o.y = f2h(leakyf(acc.y*rd, 0.01f));
  o.z = f2h(leakyf(acc.z*rd, 0.01f)); o.w = f2h(leakyf(acc.w*rd, 0.01f));
  *(ushort4*)(sems + (size_t)(semo[g]+n)*256 + lane*4) = o;
}

// beta inline + combine; fp32 outputs (nontemporal) + fp16 gather copies; grid 5000
__global__ __launch_bounds__(256) void sem_combine(const ushort* __restrict__ sems,
    const float* __restrict__ tsum, float* __restrict__ lemb, float* __restrict__ demb,
    ushort* __restrict__ lemb16, ushort* __restrict__ demb16){
  float wl0 = tsum[0]*(1.f/20000.f), wl1 = tsum[1]*(1.f/20000.f);
  float m = fmaxf(wl0,wl1);
  float ea = __expf(wl0-m), eb = __expf(wl1-m);
  float b0 = ea/(ea+eb), b1 = eb/(ea+eb);
  float wd0 = tsum[2]*(1.f/20000.f), wd1 = tsum[3]*(1.f/20000.f);
  m = fmaxf(wd0,wd1);
  ea = __expf(wd0-m); eb = __expf(wd1-m);
  float b2 = ea/(ea+eb), b3 = eb/(ea+eb);

  long idx = (long)blockIdx.x*256 + threadIdx.x;
  long r = idx>>6; int c4 = (int)(idx&63)<<2;
  ushort4 v1 = *(const ushort4*)(sems + (r          )*256 + c4);
  ushort4 v2 = *(const ushort4*)(sems + (r + 20000L )*256 + c4);
  ushort4 v0 = *(const ushort4*)(sems + (r + 40000L )*256 + c4);
  ushort4 v3 = *(const ushort4*)(sems + (r + 60000L )*256 + c4);
  f32x4 lo, dd;
  lo[0] = b0*h2f(v1.x) + b1*h2f(v2.x); dd[0] = b2*h2f(v0.x) + b3*h2f(v3.x);
  lo[1] = b0*h2f(v1.y) + b1*h2f(v2.y); dd[1] = b2*h2f(v0.y) + b3*h2f(v3.y);
  lo[2] = b0*h2f(v1.z) + b1*h2f(v2.z); dd[2] = b2*h2f(v0.z) + b3*h2f(v3.z);
  lo[3] = b0*h2f(v1.w) + b1*h2f(v2.w); dd[3] = b2*h2f(v0.w) + b3*h2f(v3.w);
  nts4(lemb + r*256 + c4, lo);
  nts4(demb + r*256 + c4, dd);
  ushort4 lh, dh;
  lh.x=f2h(lo[0]); lh.y=f2h(lo[1]); lh.z=f2h(lo[2]); lh.w=f2h(lo[3]);
  dh.x=f2h(dd[0]); dh.y=f2h(dd[1]); dh.z=f2h(dd[2]); dh.w=f2h(dd[3]);
  *(ushort4*)(lemb16 + r*256 + c4) = lh;
  *(ushort4*)(demb16 + r*256 + c4) = dh;
}

// pos+neg in one launch, fp16 gathers (8B/lane), nt stores (16B/lane); grid 80000
__global__ __launch_bounds__(256) void edge_mul2(const int* __restrict__ ps, const int* __restrict__ pd,
    const int* __restrict__ ns, const int* __restrict__ nd,
    const ushort* __restrict__ lemb16, const ushort* __restrict__ demb16,
    float* __restrict__ pos, float* __restrict__ neg){
  long idx = (long)blockIdx.x*256 + threadIdx.x;
  const long H = (long)NE*64;
  const int *es, *ed; float* out; long t;
  if (idx < H){ es=ps; ed=pd; out=pos; t=idx; }
  else { es=ns; ed=nd; out=neg; t=idx-H; }
  long i = t>>6; int jj = (int)(t&63);
  int s = es[i], d = ed[i];
  ushort4 a = *(const ushort4*)(lemb16 + (size_t)s*256 + (size_t)jj*4);
  ushort4 b = *(const ushort4*)(demb16 + (size_t)d*256 + (size_t)jj*4);
  f32x4 o;
  o[0]=h2f(a.x)*h2f(b.x); o[1]=h2f(a.y)*h2f(b.y);
  o[2]=h2f(a.z)*h2f(b.z); o[3]=h2f(a.w)*h2f(b.w);
  nts4(out + (size_t)t*4, o);
}

extern "C" void kernel_launch(void* const* d_in, const int* in_sizes, int n_in,
                              void* d_out, int out_size, void* d_ws, size_t ws_size,
                              hipStream_t stream){
  const float* x_lnc  = (const float*)d_in[0];
  const float* x_dis  = (const float*)d_in[1];
  const float* proj_W = (const float*)d_in[2];
  const float* bn_g   = (const float*)d_in[3];
  const float* bn_b   = (const float*)d_in[4];
  const float* short_W= (const float*)d_in[5];
  const float* short_b= (const float*)d_in[6];
  const float* gat_W  = (const float*)d_in[7];
  const float* gat_al = (const float*)d_in[8];
  const float* gat_ar = (const float*)d_in[9];
  const float* sem_W1 = (const float*)d_in[10];
  const float* sem_b1 = (const float*)d_in[11];
  const float* sem_w2 = (const float*)d_in[12];
  const int* g_src[4] = {(const int*)d_in[13],(const int*)d_in[15],(const int*)d_in[17],(const int*)d_in[19]};
  const int* g_dst[4] = {(const int*)d_in[14],(const int*)d_in[16],(const int*)d_in[18],(const int*)d_in[20]};
  const int* pos_src = (const int*)d_in[21];
  const int* pos_dst = (const int*)d_in[22];
  const int* neg_src = (const int*)d_in[23];
  const int* neg_dst = (const int*)d_in[24];

  const long LEMB = (long)NN*256;
  const long EOUT = (long)NE*256;

  float* outf = (float*)d_out;
  float* pos  = outf;
  float* negr = outf + EOUT;
  float* lemb = outf + 2*EOUT;
  float* demb = lemb + LEMB;

  // fp16 scratch in d_out neg region (dead before edge_mul2 writes it):
  ushort* PS_l = (ushort*)negr;            // [20000][512] fp16
  ushort* PS_d = PS_l + 10240000;
  ushort* fc_l = (ushort*)negr;            // [20000][768] fp16 (after PS dead)
  ushort* fc_d = fc_l + 15360000;

  float* ws   = (float*)d_ws;
  float* sbuf = ws;                            // 1024 (zeroed by prep)
  float* tsum = ws + 1024;                     // 4   (zeroed)
  int*   cnt  = (int*)(ws + 1028);             // 80000 (zeroed) -> fill span 81028 words
  float* elr_l = ws + 81028;                   // 640000 (packed [n][32] fp32)
  float* elr_d = elr_l + 640000;               // 640000
  int*   slots  = (int*)(elr_d + 640000);      // 3,200,000
  ushort* xhl  = (ushort*)(slots + 3200000);   // 5,120,000
  ushort* xhd  = xhl + 5120000;
  ushort* axl  = xhd + 5120000;
  ushort* axd  = axl + 5120000;
  ushort* sems = axd + 5120000;                // 20,480,000
  ushort* lemb16 = sems + 20480000;            // 5,120,000
  ushort* demb16 = lemb16 + 5120000;
  ushort* btpl = demb16 + 5120000;             // 512*256
  ushort* btpd = btpl + 131072;                // 512*256
  ushort* btgl = btpd + 131072;                // 896*256
  ushort* btgd = btgl + 229376;                // 896*256
  ushort* btsm = btgd + 229376;                // 128*256

  prep<<<10645,256,0,stream>>>(x_lnc, x_dis, proj_W, short_W, gat_W, gat_al, gat_ar,
                               sem_W1, xhl, xhd, btpl, btpd, btgl, btgd, btsm, (int*)ws);

  // stage 1: proj+shortcut GEMM (fused bn stats; z=2 overlaps the edge scatter)
  gemm16<1><<<dim3(4,157,3),256,0,stream>>>(xhl, xhd, btpl, btpd, PS_l, PS_d, 512, NN,
      sbuf, nullptr, nullptr, nullptr, nullptr,
      g_src[0],g_src[1],g_src[2],g_src[3], g_dst[0],g_dst[1],g_dst[2],g_dst[3],
      cnt, slots);
  proj_apply2<<<dim3(5000,2),256,0,stream>>>(PS_l, PS_d, sbuf, bn_g, bn_b, short_b, axl, axd);

  // stage 2: GAT fc GEMM; col-block 6 emits packed fp32 el/er
  gemm16<2><<<dim3(7,157,2),256,0,stream>>>(axl, axd, btgl, btgd, fc_l, fc_d, 768, NN,
      nullptr, elr_l, elr_d, nullptr, nullptr,
      nullptr,nullptr,nullptr,nullptr, nullptr,nullptr,nullptr,nullptr, nullptr,nullptr);

  // fused GAT (shift-free softmax + aggregate), writes stacked fp16 [e1;e2;e0;e3]
  gat_fused<<<dim3(5000,4),256,0,stream>>>(cnt, slots, elr_l, elr_d, fc_l, fc_d, sems);

  // semantic attention GEMM with fused tanh-dot epilogue
  gemm16<3><<<dim3(1,625,1),256,0,stream>>>(sems, nullptr, btsm, nullptr, nullptr, nullptr, 128, 80000,
      tsum, nullptr, nullptr, sem_b1, sem_w2,
      nullptr,nullptr,nullptr,nullptr, nullptr,nullptr,nullptr,nullptr, nullptr,nullptr);

  // beta (inline) + combine -> fp32 outputs (nt) + fp16 gather copies
  sem_combine<<<5000,256,0,stream>>>(sems, tsum, lemb, demb, lemb16, demb16);

  // link outputs (nt stores)
  edge_mul2<<<80000,256,0,stream>>>(pos_src, pos_dst, neg_src, neg_dst, lemb16, demb16, pos, negr);
}